// Round 1
// baseline (436.610 us; speedup 1.0000x reference)
//
#include <hip/hip_runtime.h>
#include <math.h>

typedef unsigned short u16;
typedef u16   u16x8  __attribute__((ext_vector_type(8)));
typedef u16   u16x4  __attribute__((ext_vector_type(4)));
typedef __bf16 bf16x8 __attribute__((ext_vector_type(8)));
typedef float f32x4  __attribute__((ext_vector_type(4)));

// B=4 S=1024 E=768 H=8 HD=96 FF=3072
#define SZ_BSE   3145728   // 4*1024*768
#define SZ_PROBS 33554432  // 4*8*1024*1024
#define HEADSZ   98304     // 1024*96
#define SCALING  0.10206207261596577f

__device__ __forceinline__ u16 f2bf(float f) {
  union { float f; unsigned u; } c; c.f = f;
  unsigned u = c.u;
  return (u16)((u + 0x7fffu + ((u >> 16) & 1u)) >> 16);
}

// ---------------- fp32 -> bf16 convert (weights) ----------------
__global__ __launch_bounds__(256) void cvt_k(const float* __restrict__ in,
                                             u16* __restrict__ out, int n) {
  int i = (blockIdx.x * 256 + threadIdx.x) * 4;
  if (i >= n) return;
  f32x4 v = *(const f32x4*)&in[i];
  u16x4 o; o[0]=f2bf(v[0]); o[1]=f2bf(v[1]); o[2]=f2bf(v[2]); o[3]=f2bf(v[3]);
  *(u16x4*)&out[i] = o;
}

// ---------------- LayerNorm (row of 768) -> bf16 ----------------
__global__ __launch_bounds__(256) void ln_k(const float* __restrict__ x,
                                            const float* __restrict__ g,
                                            const float* __restrict__ b,
                                            u16* __restrict__ out) {
  const int row = blockIdx.x;
  const float* xr = x + (long)row * 768;
  const int t = threadIdx.x;
  float v0 = xr[t], v1 = xr[t + 256], v2 = xr[t + 512];
  float s = v0 + v1 + v2, ss = v0*v0 + v1*v1 + v2*v2;
  for (int o = 32; o > 0; o >>= 1) { s += __shfl_xor(s, o); ss += __shfl_xor(ss, o); }
  __shared__ float red[8];
  int w = t >> 6;
  if ((t & 63) == 0) { red[w] = s; red[w + 4] = ss; }
  __syncthreads();
  s  = red[0] + red[1] + red[2] + red[3];
  ss = red[4] + red[5] + red[6] + red[7];
  float mean = s * (1.0f / 768.0f);
  float var  = ss * (1.0f / 768.0f) - mean * mean;
  float rstd = rsqrtf(var + 1e-5f);
  u16* orow = out + (long)row * 768;
  orow[t]       = f2bf((v0 - mean) * rstd * g[t]       + b[t]);
  orow[t + 256] = f2bf((v1 - mean) * rstd * g[t + 256] + b[t + 256]);
  orow[t + 512] = f2bf((v2 - mean) * rstd * g[t + 512] + b[t + 512]);
}

// ---------------- softmax * SCALING, then (p + dist)*0.5, in-place ----------------
__global__ __launch_bounds__(256) void softmax_k(float* __restrict__ sc,
                                                 const float* __restrict__ dist) {
  const long row = blockIdx.x;
  float* sr = sc + row * 1024;
  const float* dr = dist + row * 1024;
  const int t = threadIdx.x;
  f32x4 x = *(const f32x4*)&sr[t * 4];
  x[0] *= SCALING; x[1] *= SCALING; x[2] *= SCALING; x[3] *= SCALING;
  float m = fmaxf(fmaxf(x[0], x[1]), fmaxf(x[2], x[3]));
  for (int o = 32; o > 0; o >>= 1) m = fmaxf(m, __shfl_xor(m, o));
  __shared__ float red[8];
  int w = t >> 6;
  if ((t & 63) == 0) red[w] = m;
  __syncthreads();
  m = fmaxf(fmaxf(red[0], red[1]), fmaxf(red[2], red[3]));
  f32x4 e;
  e[0] = expf(x[0] - m); e[1] = expf(x[1] - m);
  e[2] = expf(x[2] - m); e[3] = expf(x[3] - m);
  float s = e[0] + e[1] + e[2] + e[3];
  for (int o = 32; o > 0; o >>= 1) s += __shfl_xor(s, o);
  if ((t & 63) == 0) red[w + 4] = s;
  __syncthreads();
  s = red[4] + red[5] + red[6] + red[7];
  float inv = 1.0f / s;
  f32x4 d = *(const f32x4*)&dr[t * 4];
  f32x4 o4;
  o4[0] = (e[0] * inv + d[0]) * 0.5f;
  o4[1] = (e[1] * inv + d[1]) * 0.5f;
  o4[2] = (e[2] * inv + d[2]) * 0.5f;
  o4[3] = (e[3] * inv + d[3]) * 0.5f;
  *(f32x4*)&sr[t * 4] = o4;
}

// ---------------- V transpose per head: [1024,96] -> [96,1024] (bf16) ----------------
__global__ __launch_bounds__(256) void vtrans_k(const u16* __restrict__ v,
                                                u16* __restrict__ vt) {
  long idx = (long)blockIdx.x * 256 + threadIdx.x; // over 32*98304
  int z = (int)(idx / HEADSZ);
  int rem = (int)(idx % HEADSZ);
  int s = rem / 96, d = rem % 96;
  vt[(long)z * HEADSZ + (long)d * 1024 + s] = v[idx];
}

// ---------------- generic bf16 MFMA GEMM: C = A[M,K] @ W[N,K]^T (+epilogue) ----------------
// A is bf16 (or f32, converted during staging). Tile 128x128, BK=32, 4 waves.
enum { EPI_QKV = 0, EPI_SCORES = 1, EPI_PV = 2, EPI_RES = 3, EPI_GELU = 4 };

template <int EPI, bool AF32>
__global__ __launch_bounds__(256, 2)
void gemm_k(const void* __restrict__ Av, long sAz,
            const u16* __restrict__ W, long sWz,
            void* __restrict__ Cv, long sCz, int ldc,
            const float* __restrict__ bias,
            const float* __restrict__ resid,
            const int* __restrict__ mask,
            int N, int K) {
  __shared__ u16 sA[128][40]; // +8 pad: bank-conflict-light for ds_read_b128
  __shared__ u16 sB[128][40];

  const int t  = threadIdx.x;
  const int bz = blockIdx.z;
  const int m0 = blockIdx.x * 128;
  const int n0 = blockIdx.y * 128;

  const int srow = t >> 1;
  const int scol = (t & 1) << 4;

  const int lane = t & 63;
  const int w  = t >> 6;
  const int wm = (w >> 1) * 64, wn = (w & 1) * 64;
  const int lr = lane & 15, lg = lane >> 4;

  f32x4 acc[4][4] = {};

  const u16* Wz = W + (long)bz * sWz;
  int bn = n0 + srow; if (bn > N - 1) bn = N - 1; // clamp for N=96 tail
  const long arowoff = (long)(m0 + srow) * K + scol;
  const long wrowoff = (long)bn * K + scol;

  for (int k0 = 0; k0 < K; k0 += 32) {
    if (AF32) {
      const float* Ap = (const float*)Av + (long)bz * sAz + arowoff + k0;
      f32x4 a0 = *(const f32x4*)(Ap);
      f32x4 a1 = *(const f32x4*)(Ap + 4);
      f32x4 a2 = *(const f32x4*)(Ap + 8);
      f32x4 a3 = *(const f32x4*)(Ap + 12);
      u16x8 p0, p1;
      p0[0]=f2bf(a0[0]); p0[1]=f2bf(a0[1]); p0[2]=f2bf(a0[2]); p0[3]=f2bf(a0[3]);
      p0[4]=f2bf(a1[0]); p0[5]=f2bf(a1[1]); p0[6]=f2bf(a1[2]); p0[7]=f2bf(a1[3]);
      p1[0]=f2bf(a2[0]); p1[1]=f2bf(a2[1]); p1[2]=f2bf(a2[2]); p1[3]=f2bf(a2[3]);
      p1[4]=f2bf(a3[0]); p1[5]=f2bf(a3[1]); p1[6]=f2bf(a3[2]); p1[7]=f2bf(a3[3]);
      *(u16x8*)&sA[srow][scol]     = p0;
      *(u16x8*)&sA[srow][scol + 8] = p1;
    } else {
      const u16* Ap = (const u16*)Av + (long)bz * sAz + arowoff + k0;
      *(u16x8*)&sA[srow][scol]     = *(const u16x8*)(Ap);
      *(u16x8*)&sA[srow][scol + 8] = *(const u16x8*)(Ap + 8);
    }
    {
      const u16* Wp = Wz + wrowoff + k0;
      *(u16x8*)&sB[srow][scol]     = *(const u16x8*)(Wp);
      *(u16x8*)&sB[srow][scol + 8] = *(const u16x8*)(Wp + 8);
    }
    __syncthreads();

    bf16x8 aF[4], bF[4];
#pragma unroll
    for (int mi = 0; mi < 4; ++mi)
      aF[mi] = *(const bf16x8*)&sA[wm + mi * 16 + lr][lg * 8];
#pragma unroll
    for (int ni = 0; ni < 4; ++ni)
      bF[ni] = *(const bf16x8*)&sB[wn + ni * 16 + lr][lg * 8];
#pragma unroll
    for (int mi = 0; mi < 4; ++mi)
#pragma unroll
      for (int ni = 0; ni < 4; ++ni)
        acc[mi][ni] = __builtin_amdgcn_mfma_f32_16x16x32_bf16(aF[mi], bF[ni], acc[mi][ni], 0, 0, 0);
    __syncthreads();
  }

  long coff;
  if (EPI == EPI_PV) coff = (long)(bz >> 3) * 786432 + (long)(bz & 7) * 96;
  else               coff = (long)bz * sCz;

#pragma unroll
  for (int mi = 0; mi < 4; ++mi) {
#pragma unroll
    for (int ni = 0; ni < 4; ++ni) {
      int gc = n0 + wn + ni * 16 + lr;
      if (gc >= N) continue;
      int gr0 = m0 + wm + mi * 16 + lg * 4;
#pragma unroll
      for (int r = 0; r < 4; ++r) {
        float v = acc[mi][ni][r];
        long idx = coff + (long)(gr0 + r) * ldc + gc;
        if (EPI == EPI_QKV) {
          v += bias[gc];
          ((u16*)Cv)[idx] = f2bf(v);
        } else if (EPI == EPI_SCORES) {
          if (mask[(bz >> 3) * 1024 + gc] != 0) v = -10000.0f; // mask BEFORE scaling
          ((float*)Cv)[idx] = v;
        } else if (EPI == EPI_PV) {
          ((u16*)Cv)[idx] = f2bf(v);
        } else if (EPI == EPI_RES) {
          v += bias[gc] + resid[(long)(gr0 + r) * ldc + gc];
          ((float*)Cv)[idx] = v;
        } else { // EPI_GELU (exact)
          v += bias[gc];
          v = 0.5f * v * (1.0f + erff(v * 0.70710678118654752f));
          ((u16*)Cv)[idx] = f2bf(v);
        }
      }
    }
  }
}

extern "C" void kernel_launch(void* const* d_in, const int* in_sizes, int n_in,
                              void* d_out, int out_size, void* d_ws, size_t ws_size,
                              hipStream_t stream) {
  (void)in_sizes; (void)n_in; (void)out_size; (void)ws_size;
  const float* x    = (const float*)d_in[0];
  const float* dist = (const float*)d_in[1];
  const int*   mask = (const int*)d_in[2];
  const float* Wq = (const float*)d_in[3];  const float* bq  = (const float*)d_in[4];
  const float* Wk = (const float*)d_in[5];  const float* bk  = (const float*)d_in[6];
  const float* Wv = (const float*)d_in[7];  const float* bv  = (const float*)d_in[8];
  const float* Wo = (const float*)d_in[9];  const float* bo  = (const float*)d_in[10];
  const float* g1 = (const float*)d_in[11]; const float* b1n = (const float*)d_in[12];
  const float* W1 = (const float*)d_in[13]; const float* b1f = (const float*)d_in[14];
  const float* W2 = (const float*)d_in[15]; const float* b2f = (const float*)d_in[16];
  const float* g2 = (const float*)d_in[17]; const float* b2n = (const float*)d_in[18];

  char* ws = (char*)d_ws;
  u16*   h    = (u16*)(ws + 0);
  u16*   q    = (u16*)(ws + 6291456);
  u16*   k    = (u16*)(ws + 12582912);
  u16*   v    = (u16*)(ws + 18874368);
  u16*   vT   = (u16*)(ws + 25165824);
  u16*   ctx  = (u16*)(ws + 31457280);
  u16*   h2   = (u16*)(ws + 37748736);
  u16*   ffn1 = (u16*)(ws + 44040192);
  float* x1   = (float*)(ws + 69206016);
  u16*   wqb  = (u16*)(ws + 81788928);
  u16*   wkb  = (u16*)(ws + 82968576);
  u16*   wvb  = (u16*)(ws + 84148224);
  u16*   wob  = (u16*)(ws + 85327872);
  u16*   w1b  = (u16*)(ws + 86507520);
  u16*   w2b  = (u16*)(ws + 91226112);
  // total ws use: ~96 MB

  float* outp   = (float*)d_out;
  float* scores = outp + SZ_BSE; // probs region [B,H,S,S]

  // weights -> bf16
  cvt_k<<<576,  256, 0, stream>>>(Wq, wqb, 589824);
  cvt_k<<<576,  256, 0, stream>>>(Wk, wkb, 589824);
  cvt_k<<<576,  256, 0, stream>>>(Wv, wvb, 589824);
  cvt_k<<<576,  256, 0, stream>>>(Wo, wob, 589824);
  cvt_k<<<2304, 256, 0, stream>>>(W1, w1b, 2359296);
  cvt_k<<<2304, 256, 0, stream>>>(W2, w2b, 2359296);

  // LN1
  ln_k<<<4096, 256, 0, stream>>>(x, g1, b1n, h);

  // QKV projections: [4096,768] = h @ W^T + b  -> bf16
  dim3 g768(32, 6, 1);
  gemm_k<EPI_QKV, false><<<g768, 256, 0, stream>>>(h, 0, wqb, 0, q, 0, 768, bq, nullptr, nullptr, 768, 768);
  gemm_k<EPI_QKV, false><<<g768, 256, 0, stream>>>(h, 0, wkb, 0, k, 0, 768, bk, nullptr, nullptr, 768, 768);
  gemm_k<EPI_QKV, false><<<g768, 256, 0, stream>>>(h, 0, wvb, 0, v, 0, 768, bv, nullptr, nullptr, 768, 768);

  // V transpose per head
  vtrans_k<<<12288, 256, 0, stream>>>(v, vT);

  // scores = Q @ K^T per head (masked, unscaled) -> f32 into probs region
  gemm_k<EPI_SCORES, false><<<dim3(8, 8, 32), 256, 0, stream>>>(
      q, HEADSZ, k, HEADSZ, scores, 1048576, 1024, nullptr, nullptr, mask, 1024, 96);

  // softmax(scale) + dist fusion, in-place
  softmax_k<<<32768, 256, 0, stream>>>(scores, dist);

  // ctx = probs @ V  (A = f32 probs, W = vT[96,1024]) -> bf16 ctx[B,S,E] strided per head
  gemm_k<EPI_PV, true><<<dim3(8, 1, 32), 256, 0, stream>>>(
      scores, 1048576, vT, HEADSZ, ctx, 0, 768, nullptr, nullptr, nullptr, 96, 1024);

  // x1 = x + ctx @ Wo^T + bo  -> f32
  gemm_k<EPI_RES, false><<<g768, 256, 0, stream>>>(ctx, 0, wob, 0, x1, 0, 768, bo, x, nullptr, 768, 768);

  // LN2
  ln_k<<<4096, 256, 0, stream>>>(x1, g2, b2n, h2);

  // ffn1 = gelu(h2 @ W1^T + b1) -> bf16 [4096,3072]
  gemm_k<EPI_GELU, false><<<dim3(32, 24, 1), 256, 0, stream>>>(h2, 0, w1b, 0, ffn1, 0, 3072, b1f, nullptr, nullptr, 3072, 768);

  // out = x1 + ffn1 @ W2^T + b2 -> f32
  gemm_k<EPI_RES, false><<<g768, 256, 0, stream>>>(ffn1, 0, w2b, 0, outp, 0, 768, b2f, x1, nullptr, 768, 3072);
}

// Round 2
// 324.221 us; speedup vs baseline: 1.3466x; 1.3466x over previous
//
#include <hip/hip_runtime.h>
#include <math.h>

typedef unsigned short u16;
typedef u16   u16x8  __attribute__((ext_vector_type(8)));
typedef u16   u16x4  __attribute__((ext_vector_type(4)));
typedef __bf16 bf16x8 __attribute__((ext_vector_type(8)));
typedef float f32x4  __attribute__((ext_vector_type(4)));

// B=4 S=1024 E=768 H=8 HD=96 FF=3072
#define SZ_BSE   3145728
#define HEADSZ   98304
#define SCALING  0.10206207261596577f

__device__ __forceinline__ u16 f2bf(float f) {
  union { float f; unsigned u; } c; c.f = f;
  unsigned u = c.u;
  return (u16)((u + 0x7fffu + ((u >> 16) & 1u)) >> 16);
}

typedef const __attribute__((address_space(1))) unsigned int* gas1_t;
typedef __attribute__((address_space(3))) unsigned int* las3_t;
__device__ __forceinline__ void gload16(const void* g, void* l) {
  __builtin_amdgcn_global_load_lds((gas1_t)g, (las3_t)l, 16, 0, 0);
}

// ---------------- fp32 -> bf16 convert (weights) ----------------
__global__ __launch_bounds__(256) void cvt_k(const float* __restrict__ in,
                                             u16* __restrict__ out, int n) {
  int i = (blockIdx.x * 256 + threadIdx.x) * 4;
  if (i >= n) return;
  f32x4 v = *(const f32x4*)&in[i];
  u16x4 o; o[0]=f2bf(v[0]); o[1]=f2bf(v[1]); o[2]=f2bf(v[2]); o[3]=f2bf(v[3]);
  *(u16x4*)&out[i] = o;
}

// ---------------- LayerNorm (row of 768) -> bf16 ----------------
__global__ __launch_bounds__(256) void ln_k(const float* __restrict__ x,
                                            const float* __restrict__ g,
                                            const float* __restrict__ b,
                                            u16* __restrict__ out) {
  const int row = blockIdx.x;
  const float* xr = x + (long)row * 768;
  const int t = threadIdx.x;
  float v0 = xr[t], v1 = xr[t + 256], v2 = xr[t + 512];
  float s = v0 + v1 + v2, ss = v0*v0 + v1*v1 + v2*v2;
  for (int o = 32; o > 0; o >>= 1) { s += __shfl_xor(s, o); ss += __shfl_xor(ss, o); }
  __shared__ float red[8];
  int w = t >> 6;
  if ((t & 63) == 0) { red[w] = s; red[w + 4] = ss; }
  __syncthreads();
  s  = red[0] + red[1] + red[2] + red[3];
  ss = red[4] + red[5] + red[6] + red[7];
  float mean = s * (1.0f / 768.0f);
  float var  = ss * (1.0f / 768.0f) - mean * mean;
  float rstd = rsqrtf(var + 1e-5f);
  u16* orow = out + (long)row * 768;
  orow[t]       = f2bf((v0 - mean) * rstd * g[t]       + b[t]);
  orow[t + 256] = f2bf((v1 - mean) * rstd * g[t + 256] + b[t + 256]);
  orow[t + 512] = f2bf((v2 - mean) * rstd * g[t + 512] + b[t + 512]);
}

// ---------------- softmax * SCALING, then (p + dist)*0.5, in-place ----------------
__global__ __launch_bounds__(256) void softmax_k(float* __restrict__ sc,
                                                 const float* __restrict__ dist) {
  const long row = blockIdx.x;
  float* sr = sc + row * 1024;
  const float* dr = dist + row * 1024;
  const int t = threadIdx.x;
  f32x4 x = *(const f32x4*)&sr[t * 4];
  x[0] *= SCALING; x[1] *= SCALING; x[2] *= SCALING; x[3] *= SCALING;
  float m = fmaxf(fmaxf(x[0], x[1]), fmaxf(x[2], x[3]));
  for (int o = 32; o > 0; o >>= 1) m = fmaxf(m, __shfl_xor(m, o));
  __shared__ float red[8];
  int w = t >> 6;
  if ((t & 63) == 0) red[w] = m;
  __syncthreads();
  m = fmaxf(fmaxf(red[0], red[1]), fmaxf(red[2], red[3]));
  f32x4 e;
  e[0] = expf(x[0] - m); e[1] = expf(x[1] - m);
  e[2] = expf(x[2] - m); e[3] = expf(x[3] - m);
  float s = e[0] + e[1] + e[2] + e[3];
  for (int o = 32; o > 0; o >>= 1) s += __shfl_xor(s, o);
  if ((t & 63) == 0) red[w + 4] = s;
  __syncthreads();
  s = red[4] + red[5] + red[6] + red[7];
  float inv = 1.0f / s;
  f32x4 d = *(const f32x4*)&dr[t * 4];
  f32x4 o4;
  o4[0] = (e[0] * inv + d[0]) * 0.5f;
  o4[1] = (e[1] * inv + d[1]) * 0.5f;
  o4[2] = (e[2] * inv + d[2]) * 0.5f;
  o4[3] = (e[3] * inv + d[3]) * 0.5f;
  *(f32x4*)&sr[t * 4] = o4;
}

// ---------------- V transpose per head, LDS-tiled: [1024,96] -> [96,1024] ----------------
__global__ __launch_bounds__(256) void vtrans_k(const u16* __restrict__ v,
                                                u16* __restrict__ vt) {
  __shared__ u16 tile[64 * 98]; // stride 98 to spread banks
  const int z = blockIdx.x >> 4;
  const int s0 = (blockIdx.x & 15) << 6;
  const int t = threadIdx.x;
  const u16* src = v + (long)z * HEADSZ + (long)s0 * 96;
#pragma unroll
  for (int it = 0; it < 3; ++it) {
    int i = it * 2048 + t * 8;          // over [64][96] linear
    int s = i / 96, d = i % 96;
    *(u16x8*)&tile[s * 98 + d] = *(const u16x8*)&src[i];
  }
  __syncthreads();
  u16* dst = vt + (long)z * HEADSZ + s0;
#pragma unroll
  for (int it = 0; it < 6; ++it) {
    int o = it * 1024 + t * 4;          // over [96][64]
    int d = o >> 6, s = o & 63;
    u16x4 wv;
#pragma unroll
    for (int j = 0; j < 4; ++j) wv[j] = tile[(s + j) * 98 + d];
    *(u16x4*)&dst[(long)d * 1024 + s] = wv;
  }
}

// ---------------- split-K reduce: out = resid + bias + p0+p1+p2 ----------------
__global__ __launch_bounds__(256) void reduce_k(const float* __restrict__ p,
                                                const float* __restrict__ resid,
                                                const float* __restrict__ bias,
                                                float* __restrict__ out) {
  long i = ((long)blockIdx.x * 256 + threadIdx.x) * 4;
  f32x4 a = *(const f32x4*)&p[i];
  f32x4 b = *(const f32x4*)&p[3145728 + i];
  f32x4 c = *(const f32x4*)&p[6291456 + i];
  f32x4 r = *(const f32x4*)&resid[i];
  int cb = (int)(i % 768);
  f32x4 g = *(const f32x4*)&bias[cb];
  f32x4 o;
  o[0] = r[0] + g[0] + a[0] + b[0] + c[0];
  o[1] = r[1] + g[1] + a[1] + b[1] + c[1];
  o[2] = r[2] + g[2] + a[2] + b[2] + c[2];
  o[3] = r[3] + g[3] + a[3] + b[3] + c[3];
  *(f32x4*)&out[i] = o;
}

// ---------------- MFMA GEMM, m97 structure: global_load_lds staging ----------------
// C = A[M,K] @ W[N,K]^T. Tile 128x128, BK=32, 4 waves, linear LDS [128][32].
enum { EPI_QKV = 0, EPI_SCORES = 1, EPI_PV = 2, EPI_GELU = 3, EPI_PARTIAL = 4 };

template <int EPI, bool AF32>
__global__ __launch_bounds__(256, 2)
void gemm_k(const void* __restrict__ Av, long sAz, int lda,
            const u16* __restrict__ W, long sWz, int ldw,
            void* __restrict__ Cv, long sCz, int ldc,
            const float* __restrict__ bias,
            const int* __restrict__ mask,
            int N, int K, int kchunks) {
  __shared__ u16 sA[4096]; // [128][32] linear
  __shared__ u16 sB[4096];

  const int t  = threadIdx.x;
  const int z  = blockIdx.z;
  const int bz = z / kchunks;
  const int kc = z - bz * kchunks;
  const int klen = K / kchunks;
  const int kbeg = kc * klen, kend = kbeg + klen;
  const int m0 = blockIdx.x * 128;
  const int n0 = blockIdx.y * 128;

  // staging geometry: thread t stages 16B at LDS byte (t*16 + i*4096)
  const int r0 = t >> 2;            // row within 64-row half
  const int c0 = (t & 3) << 3;      // element col offset (0,8,16,24)
  char* lA = (char*)sA + ((t >> 6) << 10); // wave-uniform LDS base
  char* lB = (char*)sB + ((t >> 6) << 10);

  int bn0 = n0 + r0;      if (bn0 > N - 1) bn0 = N - 1;
  int bn1 = n0 + 64 + r0; if (bn1 > N - 1) bn1 = N - 1;
  const u16* Wz  = W + (long)bz * sWz;
  const u16* gB0 = Wz + (long)bn0 * ldw + c0;
  const u16* gB1 = Wz + (long)bn1 * ldw + c0;

  const u16*   Ab = AF32 ? nullptr : (const u16*)Av + (long)bz * sAz;
  const float* Af = AF32 ? (const float*)Av + (long)bz * sAz : nullptr;
  const u16* gA0 = AF32 ? nullptr : Ab + (long)(m0 + r0) * lda + c0;
  const u16* gA1 = AF32 ? nullptr : gA0 + 64 * lda;
  const float* Ap = AF32 ? Af + (long)(m0 + (t >> 1)) * lda + ((t & 1) << 4) : nullptr;
  u16* aw = &sA[(t >> 1) * 32 + ((t & 1) << 4)];

  const int lane = t & 63;
  const int w  = t >> 6;
  const int wm = (w >> 1) * 64, wn = (w & 1) * 64;
  const int lr = lane & 15, lg = lane >> 4;

  f32x4 acc[4][4] = {};

  for (int k0 = kbeg; k0 < kend; k0 += 32) {
    if (AF32) {
      f32x4 a0 = *(const f32x4*)(Ap + k0);
      f32x4 a1 = *(const f32x4*)(Ap + k0 + 4);
      f32x4 a2 = *(const f32x4*)(Ap + k0 + 8);
      f32x4 a3 = *(const f32x4*)(Ap + k0 + 12);
      u16x8 p0, p1;
      p0[0]=f2bf(a0[0]); p0[1]=f2bf(a0[1]); p0[2]=f2bf(a0[2]); p0[3]=f2bf(a0[3]);
      p0[4]=f2bf(a1[0]); p0[5]=f2bf(a1[1]); p0[6]=f2bf(a1[2]); p0[7]=f2bf(a1[3]);
      p1[0]=f2bf(a2[0]); p1[1]=f2bf(a2[1]); p1[2]=f2bf(a2[2]); p1[3]=f2bf(a2[3]);
      p1[4]=f2bf(a3[0]); p1[5]=f2bf(a3[1]); p1[6]=f2bf(a3[2]); p1[7]=f2bf(a3[3]);
      *(u16x8*)aw       = p0;
      *(u16x8*)(aw + 8) = p1;
    } else {
      gload16(gA0 + k0, lA);
      gload16(gA1 + k0, lA + 4096);
    }
    gload16(gB0 + k0, lB);
    gload16(gB1 + k0, lB + 4096);
    __syncthreads();

    bf16x8 aF[4], bF[4];
#pragma unroll
    for (int mi = 0; mi < 4; ++mi)
      aF[mi] = *(const bf16x8*)&sA[(wm + mi * 16 + lr) * 32 + lg * 8];
#pragma unroll
    for (int ni = 0; ni < 4; ++ni)
      bF[ni] = *(const bf16x8*)&sB[(wn + ni * 16 + lr) * 32 + lg * 8];
#pragma unroll
    for (int mi = 0; mi < 4; ++mi)
#pragma unroll
      for (int ni = 0; ni < 4; ++ni)
        acc[mi][ni] = __builtin_amdgcn_mfma_f32_16x16x32_bf16(aF[mi], bF[ni], acc[mi][ni], 0, 0, 0);
    __syncthreads();
  }

  long coff;
  if (EPI == EPI_PV)           coff = (long)(bz >> 3) * 786432 + (long)(bz & 7) * 96;
  else if (EPI == EPI_PARTIAL) coff = (long)kc * sCz;
  else                         coff = (long)bz * sCz;

#pragma unroll
  for (int mi = 0; mi < 4; ++mi) {
#pragma unroll
    for (int ni = 0; ni < 4; ++ni) {
      int gc = n0 + wn + ni * 16 + lr;
      if (gc >= N) continue;
      int gr0 = m0 + wm + mi * 16 + lg * 4;
#pragma unroll
      for (int r = 0; r < 4; ++r) {
        float vv = acc[mi][ni][r];
        long idx = coff + (long)(gr0 + r) * ldc + gc;
        if (EPI == EPI_QKV) {
          vv += bias[gc];
          int wsel = gc >= 1536 ? 2 : (gc >= 768 ? 1 : 0);
          int c = gc - wsel * 768;
          ((u16*)Cv)[(long)wsel * 3145728 + (long)(gr0 + r) * 768 + c] = f2bf(vv);
        } else if (EPI == EPI_SCORES) {
          if (mask[(bz >> 3) * 1024 + gc] != 0) vv = -10000.0f; // mask BEFORE scaling
          ((float*)Cv)[idx] = vv;
        } else if (EPI == EPI_PV) {
          ((u16*)Cv)[idx] = f2bf(vv);
        } else if (EPI == EPI_GELU) {
          vv += bias[gc];
          vv = 0.5f * vv * (1.0f + erff(vv * 0.70710678118654752f));
          ((u16*)Cv)[idx] = f2bf(vv);
        } else { // EPI_PARTIAL
          ((float*)Cv)[idx] = vv;
        }
      }
    }
  }
}

extern "C" void kernel_launch(void* const* d_in, const int* in_sizes, int n_in,
                              void* d_out, int out_size, void* d_ws, size_t ws_size,
                              hipStream_t stream) {
  (void)in_sizes; (void)n_in; (void)out_size; (void)ws_size;
  const float* x    = (const float*)d_in[0];
  const float* dist = (const float*)d_in[1];
  const int*   mask = (const int*)d_in[2];
  const float* Wq = (const float*)d_in[3];  const float* bq  = (const float*)d_in[4];
  const float* Wk = (const float*)d_in[5];  const float* bk  = (const float*)d_in[6];
  const float* Wv = (const float*)d_in[7];  const float* bv  = (const float*)d_in[8];
  const float* Wo = (const float*)d_in[9];  const float* bo  = (const float*)d_in[10];
  const float* g1 = (const float*)d_in[11]; const float* b1n = (const float*)d_in[12];
  const float* W1 = (const float*)d_in[13]; const float* b1f = (const float*)d_in[14];
  const float* W2 = (const float*)d_in[15]; const float* b2f = (const float*)d_in[16];
  const float* g2 = (const float*)d_in[17]; const float* b2n = (const float*)d_in[18];

  char* ws = (char*)d_ws;
  // layout (bytes); partial overlaps q..h2 region (disjoint lifetimes)
  u16*   h    = (u16*)(ws + 0);          // also ctx (disjoint lifetime)
  u16*   ctx  = (u16*)(ws + 0);
  u16*   qkv  = (u16*)(ws + 6291456);    // q,k,v contiguous (3x 6291456 B)
  u16*   q    = qkv;
  u16*   k    = (u16*)(ws + 12582912);
  u16*   v    = (u16*)(ws + 18874368);
  u16*   vT   = (u16*)(ws + 25165824);
  float* part = (float*)(ws + 6291456);  // 3 planes x 12582912 B (reuse q..h2 gap)
  u16*   h2   = (u16*)(ws + 31457280);
  u16*   ffn1 = (u16*)(ws + 44040192);
  float* x1   = (float*)(ws + 69206016);
  u16*   wqkvb= (u16*)(ws + 81788928);   // [2304][768] bf16
  u16*   wob  = (u16*)(ws + 85327872);
  u16*   w1b  = (u16*)(ws + 86507520);
  u16*   w2b  = (u16*)(ws + 91226112);
  float* bqkv = (float*)(ws + 95944704); // [2304] f32

  float* outp   = (float*)d_out;
  float* scores = outp + SZ_BSE; // probs region [B,H,S,S] f32

  // weights -> bf16 (wq,wk,wv contiguous into wqkvb)
  cvt_k<<<576,  256, 0, stream>>>(Wq, wqkvb,           589824);
  cvt_k<<<576,  256, 0, stream>>>(Wk, wqkvb + 589824,  589824);
  cvt_k<<<576,  256, 0, stream>>>(Wv, wqkvb + 1179648, 589824);
  cvt_k<<<576,  256, 0, stream>>>(Wo, wob, 589824);
  cvt_k<<<2304, 256, 0, stream>>>(W1, w1b, 2359296);
  cvt_k<<<2304, 256, 0, stream>>>(W2, w2b, 2359296);
  hipMemcpyAsync(bqkv,        bq, 3072, hipMemcpyDeviceToDevice, stream);
  hipMemcpyAsync(bqkv + 768,  bk, 3072, hipMemcpyDeviceToDevice, stream);
  hipMemcpyAsync(bqkv + 1536, bv, 3072, hipMemcpyDeviceToDevice, stream);

  // LN1
  ln_k<<<4096, 256, 0, stream>>>(x, g1, b1n, h);

  // fused QKV: [4096,2304] = h @ Wqkv^T + b -> routed to q|k|v bf16
  gemm_k<EPI_QKV, false><<<dim3(32, 18, 1), 256, 0, stream>>>(
      h, 0, 768, wqkvb, 0, 768, qkv, 0, 768, bqkv, nullptr, 2304, 768, 1);

  // V transpose per head
  vtrans_k<<<512, 256, 0, stream>>>(v, vT);

  // scores = Q @ K^T per head (masked, unscaled) -> f32 probs region
  gemm_k<EPI_SCORES, false><<<dim3(8, 8, 32), 256, 0, stream>>>(
      q, HEADSZ, 96, k, HEADSZ, 96, scores, 1048576, 1024, nullptr, mask, 1024, 96, 1);

  // softmax(scale) + dist fusion, in-place
  softmax_k<<<32768, 256, 0, stream>>>(scores, dist);

  // ctx = probs @ V (A f32 reg-staged), strided bf16 ctx[B,S,E]
  gemm_k<EPI_PV, true><<<dim3(8, 1, 32), 256, 0, stream>>>(
      scores, 1048576, 1024, vT, HEADSZ, 1024, ctx, 0, 768, nullptr, nullptr, 96, 1024, 1);

  // Wo: split-K x3 partials, then x1 = x + bo + sum
  gemm_k<EPI_PARTIAL, false><<<dim3(32, 6, 3), 256, 0, stream>>>(
      ctx, 0, 768, wob, 0, 768, part, 3145728, 768, nullptr, nullptr, 768, 768, 3);
  reduce_k<<<3072, 256, 0, stream>>>(part, x, bo, x1);

  // LN2
  ln_k<<<4096, 256, 0, stream>>>(x1, g2, b2n, h2);

  // ffn1 = gelu(h2 @ W1^T + b1) bf16
  gemm_k<EPI_GELU, false><<<dim3(32, 24, 1), 256, 0, stream>>>(
      h2, 0, 768, w1b, 0, 768, ffn1, 0, 3072, b1f, nullptr, 3072, 768, 1);

  // FFN2: split-K x3 partials, then out = x1 + b2 + sum
  gemm_k<EPI_PARTIAL, false><<<dim3(32, 6, 3), 256, 0, stream>>>(
      ffn1, 0, 3072, w2b, 0, 3072, part, 3145728, 768, nullptr, nullptr, 768, 3072, 3);
  reduce_k<<<3072, 256, 0, stream>>>(part, x1, b2f, outp);
}